// Round 4
// baseline (117.595 us; speedup 1.0000x reference)
//
#include <hip/hip_runtime.h>
#include <hip/hip_bf16.h>

#define BATCH 8
#define CH    64
#define CH2   32
#define NN    4096
#define BN    (BATCH * NN)   // 32768 rows total
#define KPAD  72             // LDS key-tile row stride (elements)
#define VPAD  136            // LDS value-tile row stride (elements, 128 keys + pad)
#define YPAD  36             // flash epilogue transpose row stride (floats)
#define RPAD  40             // reduce_proj LDS row stride (bf16 elements, 16B-aligned)
#define MAXSPLIT 8

typedef __attribute__((ext_vector_type(8)))  short        short8;    // 8 bf16 (MFMA A/B frag)
typedef __attribute__((ext_vector_type(4)))  float        floatx4;   // 16x16 MFMA C/D frag
typedef __attribute__((ext_vector_type(16))) float        floatx16;  // 32x32 MFMA C/D frag
typedef __attribute__((ext_vector_type(4)))  unsigned int uint4v;
typedef __attribute__((ext_vector_type(8)))  unsigned short ushort8v;
typedef __attribute__((ext_vector_type(4)))  unsigned short ushort4v;
typedef unsigned short ushort_t;

#define LOG2E      1.4426950408889634f
#define SQRT_LOG2E 1.2011224087864498f   // sqrt(log2(e)); Q,K both scaled -> S in log2 units

__device__ __forceinline__ unsigned short f2bf_rne(float f) {
    unsigned int u = __float_as_uint(f);
    return (unsigned short)((u + 0x7FFFu + ((u >> 16) & 1u)) >> 16);
}

// ---- fused prep.
// R11: occupancy fix — 2 blocks/CU (8 waves) was latency-bound. Now 32 rows per
// block, 8 threads/row, grid 1024 (4 blocks/CU, 16 waves/CU). x-tile staged via
// LDS: global loads are coalesced 128B-per-plane; per-thread work drops 2x.
__global__ __launch_bounds__(256) void prep_fused(const float* __restrict__ x,
                                                  const float* __restrict__ gw,
                                                  const float* __restrict__ gb,
                                                  ushort_t* __restrict__ xT,
                                                  float* __restrict__ mlog,
                                                  ushort_t* __restrict__ gxT) {
    __shared__ float gwl[CH2 * CH];   // [o][c]
    __shared__ float gbl[CH2];
    __shared__ float xl[CH][33];      // [c][n-local], +1 pad

    const int t = threadIdx.x;
    for (int i = t; i < CH2 * CH; i += 256) gwl[i] = gw[i];
    if (t < CH2) gbl[t] = gb[t];

    const int b  = blockIdx.x >> 7;          // 128 blocks per batch
    const int n0 = (blockIdx.x & 127) * 32;

    // stage x-tile [64c x 32n]: lane nl=t&31 consecutive-n, 8 c-planes per instr
    {
        const int nl = t & 31, cg = (t >> 5) * 8;
        const float* xpp = x + ((size_t)b * CH + cg) * NN + n0 + nl;
        #pragma unroll
        for (int j = 0; j < 8; ++j) xl[cg + j][nl] = xpp[(size_t)j * NN];
    }
    __syncthreads();

    const int row = t >> 3;        // 0..31 local row
    const int o8  = t & 7;         // channel-eighth
    const int n   = n0 + row;
    const int growg = b * NN + n;  // global row

    float xv[8];
    #pragma unroll
    for (int j = 0; j < 8; ++j) xv[j] = xl[o8 * 8 + j][row];

    // norm partial (8 ch) + bf16 pack + store (8 lanes -> 128B contiguous)
    float ns = 0.f;
    short8 v0;
    #pragma unroll
    for (int j = 0; j < 8; ++j) {
        ns += xv[j] * xv[j];
        v0[j] = (short)f2bf_rne(xv[j] * SQRT_LOG2E);
    }
    *(short8*)(xT + (size_t)growg * CH + o8 * 8) = v0;
    ns += __shfl_xor(ns, 1);
    ns += __shfl_xor(ns, 2);
    ns += __shfl_xor(ns, 4);
    if (o8 == 0) mlog[growg] = 12.0f * sqrtf(ns) * LOG2E;

    // g-projection: 8 ch x 32 out fma, then 8-lane tree reduce
    float acc[CH2];
    #pragma unroll
    for (int o = 0; o < CH2; ++o) {
        const float4* wr = (const float4*)(gwl + o * CH + o8 * 8);
        float4 w0 = wr[0], w1 = wr[1];
        acc[o] = w0.x * xv[0] + w0.y * xv[1] + w0.z * xv[2] + w0.w * xv[3]
               + w1.x * xv[4] + w1.y * xv[5] + w1.z * xv[6] + w1.w * xv[7];
    }
    #pragma unroll
    for (int o = 0; o < CH2; ++o) {
        acc[o] += __shfl_xor(acc[o], 1);
        acc[o] += __shfl_xor(acc[o], 2);
        acc[o] += __shfl_xor(acc[o], 4);
    }
    #pragma unroll
    for (int i = 0; i < 4; ++i) {
        int o = o8 * 4 + i;
        gxT[((size_t)b * CH2 + o) * NN + n] = f2bf_rne(acc[o] + gbl[o]);
    }
}

// ---- flash attention, S^T formulation (32x32x16 MFMA).
// R11: 128-key LDS tiles (iters/block 8 -> 4): half the barriers and barrier
// drains. V fragments read per-subtile (2 at a time) to hold VGPR under the
// (256,4) budget. Keeps R10's scalar-l + mlC-as-C-operand structure.
__global__ __launch_bounds__(256, 4) void flash_attn(const ushort_t* __restrict__ xT,
                                                     const ushort_t* __restrict__ gxT,
                                                     const float* __restrict__ mlog,
                                                     ushort_t* __restrict__ py,
                                                     float* __restrict__ pl,
                                                     int ksplit) {
    __shared__ __align__(16) unsigned char smem[(128 * KPAD + 32 * VPAD) * 2];  // 27136 B
    ushort_t* Klds = (ushort_t*)smem;               // 128 x KPAD bf16
    ushort_t* Vlds = Klds + 128 * KPAD;             // 32 x VPAD bf16

    const int tid = threadIdx.x, wave = tid >> 6, lane = tid & 63;
    const int q5 = lane & 31;
    const int h  = lane >> 5;
    const int bq = blockIdx.x & 255;
    const int sp = blockIdx.x >> 8;
    const int b = bq >> 5, qt = bq & 31;
    const int n0 = qt * 128 + wave * 32;
    const int k0 = sp * ksplit;

    short8 qf[4];
    {
        const ushort_t* qp = xT + ((size_t)(b * NN + n0 + q5)) * CH + h * 8;
        #pragma unroll
        for (int f = 0; f < 4; ++f) qf[f] = *(const short8*)(qp + f * 16);
    }
    const float ml = mlog[(size_t)b * NN + n0 + q5];

    floatx16 mlC;                         // persistent C operand: softmax shift
    #pragma unroll
    for (int i = 0; i < 16; ++i) mlC[i] = -ml;

    floatx16 yt;
    #pragma unroll
    for (int i = 0; i < 16; ++i) yt[i] = 0.f;
    float lsum = 0.f;

    const ushort_t* kb = xT + (size_t)(b * NN + k0) * CH;
    const ushort_t* vb = gxT + (size_t)b * CH2 * NN + k0;
    const int iters = ksplit >> 7;                    // 128 keys per iteration
    const int skey = tid >> 3, sc0 = (tid & 7) * 8;   // K stage: 4 rows/thread
    const int vc0 = (tid & 7) * 16;                   // V stage: 2x short8/thread

    for (int kt = 0; kt < iters; ++kt) {
        const size_t kof = (size_t)kt << 13;          // 128 rows x 64 ch
        short8 gk0 = *(const short8*)(kb + kof + (size_t)(skey     ) * CH + sc0);
        short8 gk1 = *(const short8*)(kb + kof + (size_t)(skey + 32) * CH + sc0);
        short8 gk2 = *(const short8*)(kb + kof + (size_t)(skey + 64) * CH + sc0);
        short8 gk3 = *(const short8*)(kb + kof + (size_t)(skey + 96) * CH + sc0);
        short8 gv0 = *(const short8*)(vb + (size_t)skey * NN + kt * 128 + vc0);
        short8 gv1 = *(const short8*)(vb + (size_t)skey * NN + kt * 128 + vc0 + 8);

        __syncthreads();                  // prior tile's reads complete
        *(short8*)(&Klds[(skey     ) * KPAD + sc0]) = gk0;
        *(short8*)(&Klds[(skey + 32) * KPAD + sc0]) = gk1;
        *(short8*)(&Klds[(skey + 64) * KPAD + sc0]) = gk2;
        *(short8*)(&Klds[(skey + 96) * KPAD + sc0]) = gk3;
        *(short8*)(&Vlds[skey * VPAD + vc0])     = gv0;
        *(short8*)(&Vlds[skey * VPAD + vc0 + 8]) = gv1;
        __syncthreads();                  // publish tile kt

        #pragma unroll
        for (int T = 0; T < 4; ++T) {
            floatx16 st;
            __builtin_amdgcn_s_setprio(1);
            {
                short8 kf = *(const short8*)(&Klds[(T * 32 + q5) * KPAD + h * 8]);
                st = __builtin_amdgcn_mfma_f32_32x32x16_bf16(kf, qf[0], mlC, 0, 0, 0);
            }
            #pragma unroll
            for (int f = 1; f < 4; ++f) {
                short8 kf = *(const short8*)(&Klds[(T * 32 + q5) * KPAD + f * 16 + h * 8]);
                st = __builtin_amdgcn_mfma_f32_32x32x16_bf16(kf, qf[f], st, 0, 0, 0);
            }
            __builtin_amdgcn_s_setprio(0);
            // P = exp2(st); accumulate l in f32; pack pairs to bf16 (RNE)
            unsigned int d[8];
            #pragma unroll
            for (int r2 = 0; r2 < 8; ++r2) {
                float p0 = __builtin_amdgcn_exp2f(st[2 * r2]);
                float p1 = __builtin_amdgcn_exp2f(st[2 * r2 + 1]);
                lsum += p0;
                lsum += p1;
                unsigned int pk;
                asm("v_cvt_pk_bf16_f32 %0, %1, %2" : "=v"(pk) : "v"(p0), "v"(p1));
                d[r2] = pk;
            }
            // P^T B-frags: lane^32 exchange via permlane32_swap
            #pragma unroll
            for (int fp = 0; fp < 2; ++fp) {
                unsigned int b0 = d[fp * 4 + 0], b1 = d[fp * 4 + 1];
                unsigned int b2 = d[fp * 4 + 2], b3 = d[fp * 4 + 3];
                asm("v_permlane32_swap_b32 %0, %1" : "+v"(b0), "+v"(b2));
                asm("v_permlane32_swap_b32 %0, %1" : "+v"(b1), "+v"(b3));
                uint4v bv;
                bv[0] = b0; bv[1] = b1; bv[2] = b2; bv[3] = b3;
                short8 pb = __builtin_bit_cast(short8, bv);
                short8 vf = *(const short8*)(&Vlds[q5 * VPAD + T * 32 + fp * 16 + h * 8]);
                __builtin_amdgcn_s_setprio(1);
                yt = __builtin_amdgcn_mfma_f32_32x32x16_bf16(vf, pb, yt, 0, 0, 0);
                __builtin_amdgcn_s_setprio(0);
            }
        }
    }

    // fold the two key-halves of lsum
    lsum += __shfl_xor(lsum, 32);

    // epilogue: transpose y^T via LDS (aliases K buffer; drain reads first)
    __syncthreads();
    float* yb = (float*)smem + wave * 32 * YPAD;
    #pragma unroll
    for (int reg = 0; reg < 16; ++reg) {
        int o = (reg & 3) + 8 * (reg >> 2) + 4 * h;
        yb[q5 * YPAD + o] = yt[reg];
    }
    __syncthreads();
    {
        int qq = lane >> 1, half = lane & 1;
        const float* src = yb + qq * YPAD + half * 16;
        float4 s0 = *(const float4*)(src);
        float4 s1 = *(const float4*)(src + 4);
        float4 s2 = *(const float4*)(src + 8);
        float4 s3 = *(const float4*)(src + 12);
        ushort8v pk0, pk1;
        pk0[0] = f2bf_rne(s0.x); pk0[1] = f2bf_rne(s0.y);
        pk0[2] = f2bf_rne(s0.z); pk0[3] = f2bf_rne(s0.w);
        pk0[4] = f2bf_rne(s1.x); pk0[5] = f2bf_rne(s1.y);
        pk0[6] = f2bf_rne(s1.z); pk0[7] = f2bf_rne(s1.w);
        pk1[0] = f2bf_rne(s2.x); pk1[1] = f2bf_rne(s2.y);
        pk1[2] = f2bf_rne(s2.z); pk1[3] = f2bf_rne(s2.w);
        pk1[4] = f2bf_rne(s3.x); pk1[5] = f2bf_rne(s3.y);
        pk1[6] = f2bf_rne(s3.z); pk1[7] = f2bf_rne(s3.w);
        ushort_t* dst = py + ((size_t)sp * BN + (size_t)b * NN + n0 + qq) * CH2 + half * 16;
        *(ushort8v*)(dst)     = pk0;
        *(ushort8v*)(dst + 8) = pk1;
    }
    if (h == 0) pl[(size_t)sp * BN + (size_t)b * NN + n0 + q5] = lsum;
}

// ---- reduce+proj: two-phase, MFMA projection.
// R11: 512-thread blocks (grid 512 -> 16 waves/CU, was 8). Phase A: 8B py loads,
// all 8 split-partials in flight. Phase B: 8 waves, 2 ct-tiles each.
__global__ __launch_bounds__(512) void reduce_proj(const ushort_t* __restrict__ py,
                                                   const float* __restrict__ pl,
                                                   const float* __restrict__ Ww,
                                                   const float* __restrict__ Wb,
                                                   const float* __restrict__ x,
                                                   float* __restrict__ out,
                                                   int nsplit) {
    __shared__ ushort_t WwB[CH * RPAD];
    __shared__ ushort_t Y[64 * RPAD];
    __shared__ float    linv[64];
    __shared__ float    WbL[CH];

    const int t = threadIdx.x;
    const int grow0 = blockIdx.x * 64;

    if (t < 256) {
        const int r = t >> 2, o8 = (t & 3) * 8;
        const float* wp = Ww + r * CH2 + o8;
        ushort8v w;
        #pragma unroll
        for (int j = 0; j < 8; ++j) w[j] = f2bf_rne(wp[j]);
        *(ushort8v*)(&WwB[r * RPAD + o8]) = w;
    }
    if (t < CH) WbL[t] = Wb[t];
    if (t < 64) {
        const float* plp = pl + grow0 + t;
        float lv[MAXSPLIT];
        #pragma unroll
        for (int s = 0; s < MAXSPLIT; ++s) {
            int sc = s < nsplit ? s : 0;
            lv[s] = plp[(size_t)sc * BN];
        }
        float l = 0.f;
        #pragma unroll
        for (int s = 0; s < MAXSPLIT; ++s) if (s < nsplit) l += lv[s];
        linv[t] = 1.0f / l;
    }

    const int row = t >> 3, o4 = (t & 7) * 4;
    float acc[4] = {0.f, 0.f, 0.f, 0.f};
    {
        const ushort_t* pp = py + (size_t)(grow0 + row) * CH2 + o4;
        ushort4v pv[MAXSPLIT];
        #pragma unroll
        for (int s = 0; s < MAXSPLIT; ++s) {
            int sc = s < nsplit ? s : 0;
            pv[s] = *(const ushort4v*)(pp + (size_t)sc * BN * CH2);
        }
        #pragma unroll
        for (int s = 0; s < MAXSPLIT; ++s) if (s < nsplit) {
            #pragma unroll
            for (int j = 0; j < 4; ++j)
                acc[j] += __uint_as_float((unsigned int)pv[s][j] << 16);
        }
    }
    __syncthreads();
    {
        float inv = linv[row];
        ushort4v yv;
        #pragma unroll
        for (int j = 0; j < 4; ++j) yv[j] = f2bf_rne(acc[j] * inv);
        *(ushort4v*)(&Y[row * RPAD + o4]) = yv;
    }
    __syncthreads();

    const int wave = t >> 6, lane = t & 63;
    const int ql = lane & 15, quad = lane >> 4;
    const int nt = wave & 3;          // n-tile (16 rows)
    const int ctb = (wave >> 2) * 2;  // ct pair {0,1} or {2,3}
    const int b = grow0 >> 12;
    const int nbase = (grow0 & (NN - 1)) + nt * 16;

    short8 bfrag = *(const short8*)(&Y[(nt * 16 + ql) * RPAD + quad * 8]);
    #pragma unroll
    for (int ci = 0; ci < 2; ++ci) {
        int ct = ctb + ci;
        short8 afrag = *(const short8*)(&WwB[(ct * 16 + ql) * RPAD + quad * 8]);
        floatx4 d = (floatx4){0.f, 0.f, 0.f, 0.f};
        d = __builtin_amdgcn_mfma_f32_16x16x32_bf16(afrag, bfrag, d, 0, 0, 0);
        #pragma unroll
        for (int r = 0; r < 4; ++r) {
            int c = ct * 16 + quad * 4 + r;
            size_t oi = ((size_t)b * CH + c) * NN + nbase + ql;
            out[oi] = d[r] + WbL[c] + x[oi];
        }
    }
}

extern "C" void kernel_launch(void* const* d_in, const int* in_sizes, int n_in,
                              void* d_out, int out_size, void* d_ws, size_t ws_size,
                              hipStream_t stream) {
    const float* x  = (const float*)d_in[0];
    const float* gw = (const float*)d_in[1];
    const float* gb = (const float*)d_in[2];
    const float* Ww = (const float*)d_in[3];
    const float* Wb = (const float*)d_in[4];
    float* out = (float*)d_out;

    ushort_t* xT   = (ushort_t*)d_ws;                          // 4 MB
    ushort_t* gxT  = xT + (size_t)BN * CH;                     // 2 MB
    float*    mlog = (float*)(gxT + (size_t)BATCH * CH2 * NN); // 128 KB
    ushort_t* py   = (ushort_t*)(mlog + BN);                   // split*BN*32 bf16
    size_t base_bytes = (size_t)BN * CH * 2 + (size_t)BATCH * CH2 * NN * 2 + (size_t)BN * 4;
    int split = MAXSPLIT;
    while (split > 1 && base_bytes + (size_t)split * BN * (CH2 * 2 + 4) > ws_size)
        split >>= 1;
    float* pl = (float*)(py + (size_t)split * BN * CH2);

    hipLaunchKernelGGL(prep_fused,  dim3(BN / 32),     dim3(256), 0, stream,
                       x, gw, gb, xT, mlog, gxT);
    hipLaunchKernelGGL(flash_attn,  dim3(256 * split), dim3(256), 0, stream,
                       xT, gxT, mlog, py, pl, NN / split);
    hipLaunchKernelGGL(reduce_proj, dim3(BN / 64),     dim3(512), 0, stream,
                       py, pl, Ww, Wb, x, out, split);
}